// Round 8
// baseline (115.391 us; speedup 1.0000x reference)
//
#include <hip/hip_runtime.h>
#include <hip/hip_bf16.h>

#define N_Q 4096
#define N_D 8192
#define D_IN 768
#define REP 768
#define NENC 129
#define RDIM 4
#define KT 24   // 768/32 K-tiles

typedef __bf16 bf16_t;
typedef __bf16 bf16x4 __attribute__((ext_vector_type(4)));
typedef __bf16 bf16x8 __attribute__((ext_vector_type(8)));
typedef float f32x4 __attribute__((ext_vector_type(4)));

__device__ __forceinline__ void gload_lds16(const void* g, void* l) {
    __builtin_amdgcn_global_load_lds(
        (const __attribute__((address_space(1))) void*)g,
        (__attribute__((address_space(3))) void*)l,
        16, 0, 0);
}

__device__ __forceinline__ unsigned ldsAddr(const void* p) {
    return (unsigned)(unsigned long long)(const __attribute__((address_space(3))) char*)p;
}

template <int OFF>
__device__ __forceinline__ bf16x8 ds_read_b128_off(unsigned addr) {
    bf16x8 r;
    asm volatile("ds_read_b128 %0, %1 offset:%2" : "=v"(r) : "v"(addr), "i"(OFF));
    return r;
}

#define BAR() asm volatile("s_barrier" ::: "memory")

// ---------------- prep: all f32->bf16 casts + per-doc weight, ONE launch ----------------
__device__ __forceinline__ void cast4(const float* __restrict__ s, bf16_t* __restrict__ d, int i) {
    const float4 v = reinterpret_cast<const float4*>(s)[i];
    bf16x4 o;
    o[0] = (bf16_t)v.x; o[1] = (bf16_t)v.y; o[2] = (bf16_t)v.z; o[3] = (bf16_t)v.w;
    reinterpret_cast<bf16x4*>(d)[i] = o;
}

__global__ void prep(const float* __restrict__ X, const float* __restrict__ D,
                     const float* __restrict__ Wx, const float* __restrict__ Wd,
                     bf16_t* __restrict__ Xb, bf16_t* __restrict__ Db,
                     bf16_t* __restrict__ Wxb, bf16_t* __restrict__ Wdb,
                     const float* __restrict__ R, const float* __restrict__ enc,
                     const float* __restrict__ pos, const float* __restrict__ We_w,
                     float* __restrict__ wout) {
    constexpr int C_X  = N_Q * D_IN / 4;
    constexpr int C_D  = C_X + N_D * D_IN / 4;
    constexpr int C_WX = C_D + REP * D_IN / 4;
    constexpr int C_WD = C_WX + REP * D_IN / 4;
    const int i = blockIdx.x * blockDim.x + threadIdx.x;
    if (i < C_X)       cast4(X,  Xb,  i);
    else if (i < C_D)  cast4(D,  Db,  i - C_X);
    else if (i < C_WX) cast4(Wx, Wxb, i - C_D);
    else if (i < C_WD) cast4(Wd, Wdb, i - C_WX);
    else {
        const int j = i - C_WD;
        if (j < N_D) {
            const float r = R[j];
            int best = 0;
            float bd = fabsf(r - enc[0]);
            for (int e = 1; e < NENC; ++e) {
                const float d = fabsf(r - enc[e]);
                if (d < bd) { bd = d; best = e; }   // strict <, matches jnp.argmin
            }
            float s = 0.f;
            for (int d = 0; d < RDIM; ++d) s += pos[best * RDIM + d] * We_w[d];
            wout[j] = s;
        }
    }
}

// ---------------- pipelined 256x128 BT-GEMM core, 4 waves, ring-3 LDS ----------------
// 4 waves (2M x 2N), per-wave 128x64 of 16x16x32 frags, BK=32. Ring of 3 tiles.
// SELF-CONTAINED iterations (no register values cross a wait boundary — the R6/R7
// NaN was a cross-iteration reg hand-off of in-flight ds_read destinations):
//   iter k: P0 reads (8, buf k%3); STAGE_A(k+2); lgkm(0); MFMA0;
//           P1 reads (4, buf k%3); STAGE_B(k+2); lgkm(0); MFMA1; vmcnt(6); BAR.
// vm audit: after iter k-1's vmcnt(6), outstanding = tile k+1's 6 only; iter k adds
//   6 (stages of tile k+2) -> 12; vmcnt(6) drains exactly tile k+1 -> resident for
//   iter k+1's reads. Prologue stages tiles 0,1; vmcnt(6) drains tile 0.
// Write-safety: STAGE(k+2) hits buf (k-1)%3; all waves' reads of it retired via
//   lgkm(0) before the iter-(k-1) barrier. Tail re-stages byte-identical (benign).
// LDS tile layout: q = row*64 + kk*2, p = q ^ (((q>>7)&7)<<4)  (0-conflict, r2/r4).
// 74KB LDS/block -> 2 blocks/CU: cross-block LDS/MFMA pipe overlap (m114) replaces
// intra-wave pipelining.
__device__ __forceinline__ void gemm_core(const bf16_t* __restrict__ gAj0,
                                          const bf16_t* __restrict__ gAj1,
                                          const bf16_t* __restrict__ gAj2,
                                          const bf16_t* __restrict__ gAj3,
                                          const bf16_t* __restrict__ gBj0,
                                          const bf16_t* __restrict__ gBj1,
                                          bf16_t (*As)[8192], bf16_t (*Bs)[4096],
                                          int dOff, unsigned baseA, unsigned baseB,
                                          f32x4 (&acc)[8][4]) {
#define STAGE_A(kt) do { const int _k = (kt); const int _b = _k % 3; \
        char* _d = (char*)(As[_b]) + dOff; \
        gload_lds16(gAj0 + _k * 32, _d); \
        gload_lds16(gAj1 + _k * 32, _d + 4096); \
        gload_lds16(gAj2 + _k * 32, _d + 8192); \
        gload_lds16(gAj3 + _k * 32, _d + 12288); } while (0)
#define STAGE_B(kt) do { const int _k = (kt); const int _b = _k % 3; \
        char* _d = (char*)(Bs[_b]) + dOff; \
        gload_lds16(gBj0 + _k * 32, _d); \
        gload_lds16(gBj1 + _k * 32, _d + 4096); } while (0)

    STAGE_A(0); STAGE_B(0);
    STAGE_A(1); STAGE_B(1);
    asm volatile("s_waitcnt vmcnt(6)" ::: "memory");   // tile 0 resident (tile 1 in flight)
    BAR();

#pragma unroll 3
    for (int k = 0; k < KT; ++k) {
        const int pre = (k + 2 < KT) ? k + 2 : KT - 1;   // idempotent tail re-stage
        const unsigned aA = baseA + (unsigned)((k % 3) * 16384);
        const unsigned aB = baseB + (unsigned)((k % 3) * 8192);

        // ---- phase 0: A-frags 0-3 + B-frags 0-3, stage A(k+2), MFMA m0-3 ----
        bf16x8 a[4], b[4];
        a[0] = ds_read_b128_off<0>(aA);
        a[1] = ds_read_b128_off<1024>(aA);
        a[2] = ds_read_b128_off<2048>(aA);
        a[3] = ds_read_b128_off<3072>(aA);
        b[0] = ds_read_b128_off<0>(aB);
        b[1] = ds_read_b128_off<1024>(aB);
        b[2] = ds_read_b128_off<2048>(aB);
        b[3] = ds_read_b128_off<3072>(aB);
        STAGE_A(pre);
        asm volatile("s_waitcnt lgkmcnt(0)" ::: "memory");
        __builtin_amdgcn_sched_barrier(0);
        __builtin_amdgcn_s_setprio(1);
#pragma unroll
        for (int mi = 0; mi < 4; ++mi)
#pragma unroll
            for (int ni = 0; ni < 4; ++ni)
                acc[mi][ni] = __builtin_amdgcn_mfma_f32_16x16x32_bf16(a[mi], b[ni], acc[mi][ni], 0, 0, 0);
        __builtin_amdgcn_s_setprio(0);

        // ---- phase 1: A-frags 4-7 (reuse b), stage B(k+2), MFMA m4-7 ----
        bf16x8 c[4];
        c[0] = ds_read_b128_off<4096>(aA);
        c[1] = ds_read_b128_off<5120>(aA);
        c[2] = ds_read_b128_off<6144>(aA);
        c[3] = ds_read_b128_off<7168>(aA);
        STAGE_B(pre);
        asm volatile("s_waitcnt lgkmcnt(0)" ::: "memory");
        __builtin_amdgcn_sched_barrier(0);
        __builtin_amdgcn_s_setprio(1);
#pragma unroll
        for (int mi = 0; mi < 4; ++mi)
#pragma unroll
            for (int ni = 0; ni < 4; ++ni)
                acc[mi + 4][ni] = __builtin_amdgcn_mfma_f32_16x16x32_bf16(c[mi], b[ni], acc[mi + 4][ni], 0, 0, 0);
        __builtin_amdgcn_s_setprio(0);

        asm volatile("s_waitcnt vmcnt(6)" ::: "memory");  // drain tile k+1's 6 loads
        BAR();
    }
#undef STAGE_A
#undef STAGE_B
}

// shared addressing setup (256 threads): A staged as 4x4KB chunks, B as 2x4KB.
// physical p = t*16 + j*4096; logical q = p ^ (((p>>7)&7)<<4); row=q>>6, kbyte=q&63.
#define CORE_SETUP(Abase, Bbase, mB, nB_)                                            \
    const int t = threadIdx.x;                                                       \
    const int lane = t & 63;                                                         \
    const int wid = t >> 6;                                                          \
    const int lr = lane & 15;                                                        \
    const int lq = lane >> 4;                                                        \
    const int wr = wid >> 1;                                                         \
    const int wc = wid & 1;                                                          \
    const int dOff = wid * 1024;                                                     \
    const bf16_t* gAj[4]; const bf16_t* gBj[2];                                      \
    _Pragma("unroll")                                                                \
    for (int j = 0; j < 4; ++j) {                                                    \
        const int pj = t * 16 + j * 4096;                                            \
        const int qj = pj ^ (((pj >> 7) & 7) << 4);                                  \
        gAj[j] = (Abase) + ((mB) + (qj >> 6)) * (long)REP + ((qj & 63) >> 1);        \
    }                                                                                \
    _Pragma("unroll")                                                                \
    for (int j = 0; j < 2; ++j) {                                                    \
        const int pj = t * 16 + j * 4096;                                            \
        const int qj = pj ^ (((pj >> 7) & 7) << 4);                                  \
        gBj[j] = (Bbase) + ((nB_) + (qj >> 6)) * (long)REP + ((qj & 63) >> 1);       \
    }                                                                                \
    const int rA = wr * 128 + lr;                                                    \
    const unsigned apA = (unsigned)((rA * 64 + lq * 16) ^ (((rA >> 1) & 7) << 4));   \
    const int rB = wc * 64 + lr;                                                     \
    const unsigned apB = (unsigned)((rB * 64 + lq * 16) ^ (((rB >> 1) & 7) << 4));   \
    const unsigned baseA = ldsAddr(&As[0][0]) + apA;                                 \
    const unsigned baseB = ldsAddr(&Bs[0][0]) + apB;

// ---------------- merged projection GEMM (stacked [Xb;Db] rows) ----------------
__global__ __launch_bounds__(256, 2)
void proj_pipe(const bf16_t* __restrict__ Ain, const bf16_t* __restrict__ Wxb,
               const bf16_t* __restrict__ Wdb, const float* __restrict__ bx,
               const float* __restrict__ bd, bf16_t* __restrict__ Cout) {
    __shared__ bf16_t As[3][8192];
    __shared__ bf16_t Bs[3][4096];

    const bool isX = blockIdx.y < (N_Q / 256);
    const bf16_t* Bw = isX ? Wxb : Wdb;
    const float* bias = isX ? bx : bd;
    const long mBase = (long)blockIdx.y * 256;
    const long nBase = (long)blockIdx.x * 128;

    CORE_SETUP(Ain, Bw, mBase, nBase)

    f32x4 acc[8][4] = {};
    gemm_core(gAj[0], gAj[1], gAj[2], gAj[3], gBj[0], gBj[1],
              As, Bs, dOff, baseA, baseB, acc);

    // epilogue: bias + bf16 store. D layout: row=(l>>4)*4+j, col=l&15 per 16x16
#pragma unroll
    for (int ni = 0; ni < 4; ++ni) {
        const int col = (int)nBase + wc * 64 + ni * 16 + lr;
        const float bv = bias[col];
#pragma unroll
        for (int mi = 0; mi < 8; ++mi)
#pragma unroll
            for (int j = 0; j < 4; ++j) {
                const long row = mBase + wr * 128 + mi * 16 + lq * 4 + j;
                Cout[row * (long)REP + col] = (bf16_t)(acc[mi][ni][j] + bv);
            }
    }
}

// ---------------- fused similarity GEMM + power-sign + weighted row-reduce ----------------
__global__ __launch_bounds__(256, 2)
void sim_pipe(const bf16_t* __restrict__ A, const bf16_t* __restrict__ B,
              const float* __restrict__ wcol, float* __restrict__ partial) {
    __shared__ bf16_t As[3][8192];
    __shared__ bf16_t Bs[3][4096];
    __shared__ float red[2][256];

    const long mBase = (long)blockIdx.y * 256;
    const long nBase = (long)blockIdx.x * 128;

    CORE_SETUP(A, B, mBase, nBase)

    f32x4 acc[8][4] = {};
    gemm_core(gAj[0], gAj[1], gAj[2], gAj[3], gBj[0], gBj[1],
              As, Bs, dOff, baseA, baseB, acc);

    // epilogue: f(a)*w, reduce over n cols
    float wreg[4];
#pragma unroll
    for (int ni = 0; ni < 4; ++ni) wreg[ni] = wcol[nBase + wc * 64 + ni * 16 + lr];

#pragma unroll
    for (int mi = 0; mi < 8; ++mi)
#pragma unroll
        for (int j = 0; j < 4; ++j) {
            float s = 0.f;
#pragma unroll
            for (int ni = 0; ni < 4; ++ni) {
                const float av = acc[mi][ni][j];
                s += av * fabsf(av) * wreg[ni];
            }
            s += __shfl_xor(s, 1);
            s += __shfl_xor(s, 2);
            s += __shfl_xor(s, 4);
            s += __shfl_xor(s, 8);
            if (lr == 0) red[wc][wr * 128 + mi * 16 + lq * 4 + j] = s;
        }
    __syncthreads();
    if (t < 256)
        partial[(long)blockIdx.x * N_Q + mBase + t] = red[0][t] + red[1][t];
}

// ---------------- final: out[i] = sum_nb partial[nb][i] + We_b ----------------
__global__ void final_reduce(const float* __restrict__ partial, const float* __restrict__ We_b,
                             float* __restrict__ out) {
    int i = blockIdx.x * blockDim.x + threadIdx.x;
    if (i < N_Q) {
        float s = 0.f;
        for (int nb = 0; nb < N_D / 128; ++nb) s += partial[(long)nb * N_Q + i];
        out[i] = s + We_b[0];
    }
}

extern "C" void kernel_launch(void* const* d_in, const int* in_sizes, int n_in,
                              void* d_out, int out_size, void* d_ws, size_t ws_size,
                              hipStream_t stream) {
    const float* X    = (const float*)d_in[0];
    const float* D    = (const float*)d_in[1];
    const float* R    = (const float*)d_in[2];
    const float* Wx_w = (const float*)d_in[3];
    const float* Wx_b = (const float*)d_in[4];
    const float* Wd_w = (const float*)d_in[5];
    const float* Wd_b = (const float*)d_in[6];
    const float* We_w = (const float*)d_in[7];
    const float* We_b = (const float*)d_in[8];
    const float* enc  = (const float*)d_in[9];
    const float* pos  = (const float*)d_in[10];
    float* out = (float*)d_out;

    char* ws = (char*)d_ws;
    bf16_t* Xb   = (bf16_t*)ws; ws += (size_t)N_Q * D_IN * 2;   // [Xb;Db] contiguous
    bf16_t* Db   = (bf16_t*)ws; ws += (size_t)N_D * D_IN * 2;
    bf16_t* Wxb  = (bf16_t*)ws; ws += (size_t)REP * D_IN * 2;
    bf16_t* Wdb  = (bf16_t*)ws; ws += (size_t)REP * D_IN * 2;
    bf16_t* Xw   = (bf16_t*)ws; ws += (size_t)N_Q * REP * 2;    // [Xw;Dw] contiguous
    bf16_t* Dw   = (bf16_t*)ws; ws += (size_t)N_D * REP * 2;
    float*  wvec = (float*)ws;  ws += (size_t)N_D * 4;
    float*  part = (float*)ws;  ws += (size_t)(N_D / 128) * N_Q * 4;

    constexpr int PREP_N = (N_Q * D_IN + N_D * D_IN + 2 * REP * D_IN) / 4 + N_D;
    prep<<<(PREP_N + 255) / 256, 256, 0, stream>>>(
        X, D, Wx_w, Wd_w, Xb, Db, Wxb, Wdb, R, enc, pos, We_w, wvec);

    proj_pipe<<<dim3(REP / 128, (N_Q + N_D) / 256), 256, 0, stream>>>(
        Xb, Wxb, Wdb, Wx_b, Wd_b, Xw);

    sim_pipe<<<dim3(N_D / 128, N_Q / 256), 256, 0, stream>>>(Xw, Dw, wvec, part);

    final_reduce<<<(N_Q + 255) / 256, 256, 0, stream>>>(part, We_b, out);
}

// Round 9
// 113.538 us; speedup vs baseline: 1.0163x; 1.0163x over previous
//
#include <hip/hip_runtime.h>
#include <hip/hip_bf16.h>

#define N_Q 4096
#define N_D 8192
#define D_IN 768
#define REP 768
#define NENC 129
#define RDIM 4

typedef __bf16 bf16_t;
typedef __bf16 bf16x4 __attribute__((ext_vector_type(4)));
typedef __bf16 bf16x8 __attribute__((ext_vector_type(8)));
typedef float f32x4 __attribute__((ext_vector_type(4)));

__device__ __forceinline__ void gload_lds16(const void* g, void* l) {
    __builtin_amdgcn_global_load_lds(
        (const __attribute__((address_space(1))) void*)g,
        (__attribute__((address_space(3))) void*)l,
        16, 0, 0);
}

__device__ __forceinline__ unsigned ldsAddr(const void* p) {
    return (unsigned)(unsigned long long)(const __attribute__((address_space(3))) char*)p;
}

template <int OFF>
__device__ __forceinline__ bf16x8 ds_read_b128_off(unsigned addr) {
    bf16x8 r;
    asm volatile("ds_read_b128 %0, %1 offset:%2" : "=v"(r) : "v"(addr), "i"(OFF));
    return r;
}

#define BAR() asm volatile("s_barrier" ::: "memory")
#define LGKM0() do { asm volatile("s_waitcnt lgkmcnt(0)" ::: "memory"); \
                     __builtin_amdgcn_sched_barrier(0); } while (0)
#define VM(n) asm volatile("s_waitcnt vmcnt(" #n ")" ::: "memory")

// ---------------- prep: all f32->bf16 casts + per-doc weight, ONE launch ----------------
__device__ __forceinline__ void cast4(const float* __restrict__ s, bf16_t* __restrict__ d, int i) {
    const float4 v = reinterpret_cast<const float4*>(s)[i];
    bf16x4 o;
    o[0] = (bf16_t)v.x; o[1] = (bf16_t)v.y; o[2] = (bf16_t)v.z; o[3] = (bf16_t)v.w;
    reinterpret_cast<bf16x4*>(d)[i] = o;
}

__global__ void prep(const float* __restrict__ X, const float* __restrict__ D,
                     const float* __restrict__ Wx, const float* __restrict__ Wd,
                     bf16_t* __restrict__ Xb, bf16_t* __restrict__ Db,
                     bf16_t* __restrict__ Wxb, bf16_t* __restrict__ Wdb,
                     const float* __restrict__ R, const float* __restrict__ enc,
                     const float* __restrict__ pos, const float* __restrict__ We_w,
                     float* __restrict__ wout) {
    constexpr int C_X  = N_Q * D_IN / 4;
    constexpr int C_D  = C_X + N_D * D_IN / 4;
    constexpr int C_WX = C_D + REP * D_IN / 4;
    constexpr int C_WD = C_WX + REP * D_IN / 4;
    const int i = blockIdx.x * blockDim.x + threadIdx.x;
    if (i < C_X)       cast4(X,  Xb,  i);
    else if (i < C_D)  cast4(D,  Db,  i - C_X);
    else if (i < C_WX) cast4(Wx, Wxb, i - C_D);
    else if (i < C_WD) cast4(Wd, Wdb, i - C_WX);
    else {
        const int j = i - C_WD;
        if (j < N_D) {
            const float r = R[j];
            int best = 0;
            float bd = fabsf(r - enc[0]);
            for (int e = 1; e < NENC; ++e) {
                const float d = fabsf(r - enc[e]);
                if (d < bd) { bd = d; best = e; }   // strict <, matches jnp.argmin
            }
            float s = 0.f;
            for (int d = 0; d < RDIM; ++d) s += pos[best * RDIM + d] * We_w[d];
            wout[j] = s;
        }
    }
}

// ================= proj: R8's PROVEN 4-wave 256x128 ring-3 core (unchanged) =================
__device__ __forceinline__ void gemm_core4(const bf16_t* __restrict__ gAj0,
                                           const bf16_t* __restrict__ gAj1,
                                           const bf16_t* __restrict__ gAj2,
                                           const bf16_t* __restrict__ gAj3,
                                           const bf16_t* __restrict__ gBj0,
                                           const bf16_t* __restrict__ gBj1,
                                           bf16_t (*As)[8192], bf16_t (*Bs)[4096],
                                           int dOff, unsigned baseA, unsigned baseB,
                                           f32x4 (&acc)[8][4]) {
#define STAGE_A(kt) do { const int _k = (kt); const int _b = _k % 3; \
        char* _d = (char*)(As[_b]) + dOff; \
        gload_lds16(gAj0 + _k * 32, _d); \
        gload_lds16(gAj1 + _k * 32, _d + 4096); \
        gload_lds16(gAj2 + _k * 32, _d + 8192); \
        gload_lds16(gAj3 + _k * 32, _d + 12288); } while (0)
#define STAGE_B(kt) do { const int _k = (kt); const int _b = _k % 3; \
        char* _d = (char*)(Bs[_b]) + dOff; \
        gload_lds16(gBj0 + _k * 32, _d); \
        gload_lds16(gBj1 + _k * 32, _d + 4096); } while (0)

    STAGE_A(0); STAGE_B(0);
    STAGE_A(1); STAGE_B(1);
    VM(6);
    BAR();

#pragma unroll 3
    for (int k = 0; k < 24; ++k) {
        const int pre = (k + 2 < 24) ? k + 2 : 23;
        const unsigned aA = baseA + (unsigned)((k % 3) * 16384);
        const unsigned aB = baseB + (unsigned)((k % 3) * 8192);

        bf16x8 a[4], b[4];
        a[0] = ds_read_b128_off<0>(aA);
        a[1] = ds_read_b128_off<1024>(aA);
        a[2] = ds_read_b128_off<2048>(aA);
        a[3] = ds_read_b128_off<3072>(aA);
        b[0] = ds_read_b128_off<0>(aB);
        b[1] = ds_read_b128_off<1024>(aB);
        b[2] = ds_read_b128_off<2048>(aB);
        b[3] = ds_read_b128_off<3072>(aB);
        STAGE_A(pre);
        LGKM0();
        __builtin_amdgcn_s_setprio(1);
#pragma unroll
        for (int mi = 0; mi < 4; ++mi)
#pragma unroll
            for (int ni = 0; ni < 4; ++ni)
                acc[mi][ni] = __builtin_amdgcn_mfma_f32_16x16x32_bf16(a[mi], b[ni], acc[mi][ni], 0, 0, 0);
        __builtin_amdgcn_s_setprio(0);

        bf16x8 c[4];
        c[0] = ds_read_b128_off<4096>(aA);
        c[1] = ds_read_b128_off<5120>(aA);
        c[2] = ds_read_b128_off<6144>(aA);
        c[3] = ds_read_b128_off<7168>(aA);
        STAGE_B(pre);
        LGKM0();
        __builtin_amdgcn_s_setprio(1);
#pragma unroll
        for (int mi = 0; mi < 4; ++mi)
#pragma unroll
            for (int ni = 0; ni < 4; ++ni)
                acc[mi + 4][ni] = __builtin_amdgcn_mfma_f32_16x16x32_bf16(c[mi], b[ni], acc[mi + 4][ni], 0, 0, 0);
        __builtin_amdgcn_s_setprio(0);

        VM(6);
        BAR();
    }
#undef STAGE_A
#undef STAGE_B
}

__global__ __launch_bounds__(256, 2)
void proj_pipe(const bf16_t* __restrict__ Ain, const bf16_t* __restrict__ Wxb,
               const bf16_t* __restrict__ Wdb, const float* __restrict__ bx,
               const float* __restrict__ bd, bf16_t* __restrict__ Cout) {
    __shared__ bf16_t As[3][8192];
    __shared__ bf16_t Bs[3][4096];

    const bool isX = blockIdx.y < (N_Q / 256);
    const bf16_t* Bw = isX ? Wxb : Wdb;
    const float* bias = isX ? bx : bd;
    const long mBase = (long)blockIdx.y * 256;
    const long nBase = (long)blockIdx.x * 128;

    const int t = threadIdx.x;
    const int lane = t & 63;
    const int wid = t >> 6;
    const int lr = lane & 15;
    const int lq = lane >> 4;
    const int wr = wid >> 1;
    const int wc = wid & 1;
    const int dOff = wid * 1024;
    const bf16_t* gAj[4]; const bf16_t* gBj[2];
#pragma unroll
    for (int j = 0; j < 4; ++j) {
        const int pj = t * 16 + j * 4096;
        const int qj = pj ^ (((pj >> 7) & 7) << 4);
        gAj[j] = Ain + (mBase + (qj >> 6)) * (long)REP + ((qj & 63) >> 1);
    }
#pragma unroll
    for (int j = 0; j < 2; ++j) {
        const int pj = t * 16 + j * 4096;
        const int qj = pj ^ (((pj >> 7) & 7) << 4);
        gBj[j] = Bw + (nBase + (qj >> 6)) * (long)REP + ((qj & 63) >> 1);
    }
    const int rA = wr * 128 + lr;
    const unsigned apA = (unsigned)((rA * 64 + lq * 16) ^ (((rA >> 1) & 7) << 4));
    const int rB = wc * 64 + lr;
    const unsigned apB = (unsigned)((rB * 64 + lq * 16) ^ (((rB >> 1) & 7) << 4));
    const unsigned baseA = ldsAddr(&As[0][0]) + apA;
    const unsigned baseB = ldsAddr(&Bs[0][0]) + apB;

    f32x4 acc[8][4] = {};
    gemm_core4(gAj[0], gAj[1], gAj[2], gAj[3], gBj[0], gBj[1],
               As, Bs, dOff, baseA, baseB, acc);

#pragma unroll
    for (int ni = 0; ni < 4; ++ni) {
        const int col = (int)nBase + wc * 64 + ni * 16 + lr;
        const float bv = bias[col];
#pragma unroll
        for (int mi = 0; mi < 8; ++mi)
#pragma unroll
            for (int j = 0; j < 4; ++j) {
                const long row = mBase + wr * 128 + mi * 16 + lq * 4 + j;
                Cout[row * (long)REP + col] = (bf16_t)(acc[mi][ni][j] + bv);
            }
    }
}

// ================= sim: 256x256, 8 waves, BK=64, k-slice sub-tile 8-phase pipeline =================
// LDS: As/Bs[2 buf][2 ks][256 rows x 32 cols] bf16 (16KB sub-tiles), 128KB + red 4KB.
// Sub-tile swizzle: q = row*64 + b; p = q ^ (((q>>8)&3)<<4) (key = row bits 2-3 = lr bits 2-3;
//   granule' = lq ^ ((lr>>2)&3) -> 2-way max bank aliasing = free).
// Phase schedule per K-tile kt (verified per-thread FIFO audit; vmcnt never 0):
//   P1: rd SA0,SB0(kt) 8; stg SA1(kt+1); lgkm0; 16 MFMA (m0-3)
//   P2: rd SA0 m4-7 4 (B in regs); stg SB1(kt+1); lgkm0; 16 MFMA; VM(4); BAR
//   P3: rd SA1,SB1(kt) 8; stg SA0(kt+2); lgkm0; 16 MFMA (m0-3)
//   P4: rd SA1 m4-7 4; stg SB0(kt+2); lgkm0; 16 MFMA; VM(4); BAR
// Residency: VM(4)@P2(kt) drains SA0,SB0(kt+1) [staged P3,P4(kt-1)]; VM(4)@P4(kt) drains
//   SA1,SB1(kt+1) [staged P1,P2(kt)]; stager's own drain precedes the shared barrier.
// Overwrite: each sub-tile's last reads are lgkm0-retired >=1 barrier before its re-stage.
// Tail: clamped indices re-stage identical bytes (benign).
__global__ __launch_bounds__(512)
void sim_pipe8(const bf16_t* __restrict__ A, const bf16_t* __restrict__ B,
               const float* __restrict__ wcol, float* __restrict__ partial) {
    __shared__ bf16_t As[2][2][8192];
    __shared__ bf16_t Bs[2][2][8192];
    __shared__ float red[4][256];

    const int t = threadIdx.x;
    const int lane = t & 63;
    const int wid = t >> 6;
    const int lr = lane & 15;
    const int lq = lane >> 4;
    const int wr = wid >> 2;   // 0..1 (m half, 128 rows)
    const int wc = wid & 3;    // 0..3 (n quarter, 64 cols)
    const long mBase = (long)blockIdx.y * 256;
    const long nBase = (long)blockIdx.x * 256;
    const int dOff = wid * 1024;

    // stage source decode (inverse-swizzled): thread t, slice j: p = t*16 + j*8192
    const bf16_t* gA[2]; const bf16_t* gB[2];
#pragma unroll
    for (int j = 0; j < 2; ++j) {
        const int p = t * 16 + j * 8192;
        const int q = p ^ (((p >> 8) & 3) << 4);
        const int row = q >> 6;            // 0..255
        const int col = (q & 63) >> 1;     // 0..31 within k-slice
        gA[j] = A + (mBase + row) * (long)REP + col;
        gB[j] = B + (nBase + row) * (long)REP + col;
    }

    // ds_read bases (swizzled); frag offsets mi*1024 / ni*1024 (key bits = lr bits 2-3, invariant)
    const unsigned swz = (unsigned)((lr * 64 + lq * 16) ^ (((lr >> 2) & 3) << 4));
    const unsigned baseA = ldsAddr(&As[0][0][0]) + (unsigned)(wr * 8192) + swz;
    const unsigned baseB = ldsAddr(&Bs[0][0][0]) + (unsigned)(wc * 4096) + swz;

#define STG_A(ks, kt_) do { const int _kt = (kt_); \
        char* _d = (char*)(&As[_kt & 1][(ks)][0]) + dOff; \
        const int _ko = _kt * 64 + (ks) * 32; \
        gload_lds16(gA[0] + _ko, _d); \
        gload_lds16(gA[1] + _ko, _d + 8192); } while (0)
#define STG_B(ks, kt_) do { const int _kt = (kt_); \
        char* _d = (char*)(&Bs[_kt & 1][(ks)][0]) + dOff; \
        const int _ko = _kt * 64 + (ks) * 32; \
        gload_lds16(gB[0] + _ko, _d); \
        gload_lds16(gB[1] + _ko, _d + 8192); } while (0)

    f32x4 acc[8][4] = {};

    // prologue: kt0 fully (8 loads) + kt1 ks0 pair (4 loads); drain kt0; 4 outstanding.
    STG_A(0, 0); STG_B(0, 0); STG_A(1, 0); STG_B(1, 0);
    STG_A(0, 1); STG_B(0, 1);
    VM(4);
    BAR();

#pragma unroll 2
    for (int kt = 0; kt < 12; ++kt) {
        const unsigned bufk = (unsigned)((kt & 1) * 32768);
        const unsigned bA0 = baseA + bufk, bA1 = bA0 + 16384;
        const unsigned bB0 = baseB + bufk, bB1 = bB0 + 16384;
        const int pre1 = (kt + 1 < 12) ? kt + 1 : 11;
        const int pre2 = (kt + 2 < 12) ? kt + 2 : 11;

        bf16x8 a[4], b[4], c[4];

        // ---- P1: ks0, m0-3 x n0-3 ----
        a[0] = ds_read_b128_off<0>(bA0);
        a[1] = ds_read_b128_off<1024>(bA0);
        a[2] = ds_read_b128_off<2048>(bA0);
        a[3] = ds_read_b128_off<3072>(bA0);
        b[0] = ds_read_b128_off<0>(bB0);
        b[1] = ds_read_b128_off<1024>(bB0);
        b[2] = ds_read_b128_off<2048>(bB0);
        b[3] = ds_read_b128_off<3072>(bB0);
        STG_A(1, pre1);
        LGKM0();
        __builtin_amdgcn_s_setprio(1);
#pragma unroll
        for (int mi = 0; mi < 4; ++mi)
#pragma unroll
            for (int ni = 0; ni < 4; ++ni)
                acc[mi][ni] = __builtin_amdgcn_mfma_f32_16x16x32_bf16(a[mi], b[ni], acc[mi][ni], 0, 0, 0);
        __builtin_amdgcn_s_setprio(0);

        // ---- P2: ks0, m4-7 (B in regs) ----
        c[0] = ds_read_b128_off<4096>(bA0);
        c[1] = ds_read_b128_off<5120>(bA0);
        c[2] = ds_read_b128_off<6144>(bA0);
        c[3] = ds_read_b128_off<7168>(bA0);
        STG_B(1, pre1);
        LGKM0();
        __builtin_amdgcn_s_setprio(1);
#pragma unroll
        for (int mi = 0; mi < 4; ++mi)
#pragma unroll
            for (int ni = 0; ni < 4; ++ni)
                acc[mi + 4][ni] = __builtin_amdgcn_mfma_f32_16x16x32_bf16(c[mi], b[ni], acc[mi + 4][ni], 0, 0, 0);
        __builtin_amdgcn_s_setprio(0);
        VM(4);
        BAR();

        // ---- P3: ks1, m0-3 x n0-3 ----
        a[0] = ds_read_b128_off<0>(bA1);
        a[1] = ds_read_b128_off<1024>(bA1);
        a[2] = ds_read_b128_off<2048>(bA1);
        a[3] = ds_read_b128_off<3072>(bA1);
        b[0] = ds_read_b128_off<0>(bB1);
        b[1] = ds_read_b128_off<1024>(bB1);
        b[2] = ds_read_b128_off<2048>(bB1);
        b[3] = ds_read_b128_off<3072>(bB1);
        STG_A(0, pre2);
        LGKM0();
        __builtin_amdgcn_s_setprio(1);
#pragma unroll
        for (int mi = 0; mi < 4; ++mi)
#pragma unroll
            for (int ni = 0; ni < 4; ++ni)
                acc[mi][ni] = __builtin_amdgcn_mfma_f32_16x16x32_bf16(a[mi], b[ni], acc[mi][ni], 0, 0, 0);
        __builtin_amdgcn_s_setprio(0);

        // ---- P4: ks1, m4-7 ----
        c[0] = ds_read_b128_off<4096>(bA1);
        c[1] = ds_read_b128_off<5120>(bA1);
        c[2] = ds_read_b128_off<6144>(bA1);
        c[3] = ds_read_b128_off<7168>(bA1);
        STG_B(0, pre2);
        LGKM0();
        __builtin_amdgcn_s_setprio(1);
#pragma unroll
        for (int mi = 0; mi < 4; ++mi)
#pragma unroll
            for (int ni = 0; ni < 4; ++ni)
                acc[mi + 4][ni] = __builtin_amdgcn_mfma_f32_16x16x32_bf16(c[mi], b[ni], acc[mi + 4][ni], 0, 0, 0);
        __builtin_amdgcn_s_setprio(0);
        VM(4);
        BAR();
    }
#undef STG_A
#undef STG_B

    // epilogue: f(a)*w, reduce over n cols. D layout: row=(l>>4)*4+j, col=l&15 per 16x16
    float wreg[4];
#pragma unroll
    for (int ni = 0; ni < 4; ++ni) wreg[ni] = wcol[nBase + wc * 64 + ni * 16 + lr];

#pragma unroll
    for (int mi = 0; mi < 8; ++mi)
#pragma unroll
        for (int j = 0; j < 4; ++j) {
            float s = 0.f;
#pragma unroll
            for (int ni = 0; ni < 4; ++ni) {
                const float av = acc[mi][ni][j];
                s += av * fabsf(av) * wreg[ni];
            }
            s += __shfl_xor(s, 1);
            s += __shfl_xor(s, 2);
            s += __shfl_xor(s, 4);
            s += __shfl_xor(s, 8);
            if (lr == 0) red[wc][wr * 128 + mi * 16 + lq * 4 + j] = s;
        }
    __syncthreads();
    if (t < 256)
        partial[(long)blockIdx.x * N_Q + mBase + t]
            = red[0][t] + red[1][t] + red[2][t] + red[3][t];
}

// ---------------- final: out[i] = sum_nb partial[nb][i] + We_b ----------------
__global__ void final_reduce(const float* __restrict__ partial, const float* __restrict__ We_b,
                             float* __restrict__ out) {
    int i = blockIdx.x * blockDim.x + threadIdx.x;
    if (i < N_Q) {
        float s = 0.f;
        for (int nb = 0; nb < N_D / 256; ++nb) s += partial[(long)nb * N_Q + i];
        out[i] = s + We_b[0];
    }
}

extern "C" void kernel_launch(void* const* d_in, const int* in_sizes, int n_in,
                              void* d_out, int out_size, void* d_ws, size_t ws_size,
                              hipStream_t stream) {
    const float* X    = (const float*)d_in[0];
    const float* D    = (const float*)d_in[1];
    const float* R    = (const float*)d_in[2];
    const float* Wx_w = (const float*)d_in[3];
    const float* Wx_b = (const float*)d_in[4];
    const float* Wd_w = (const float*)d_in[5];
    const float* Wd_b = (const float*)d_in[6];
    const float* We_w = (const float*)d_in[7];
    const float* We_b = (const float*)d_in[8];
    const float* enc  = (const float*)d_in[9];
    const float* pos  = (const float*)d_in[10];
    float* out = (float*)d_out;

    char* ws = (char*)d_ws;
    bf16_t* Xb   = (bf16_t*)ws; ws += (size_t)N_Q * D_IN * 2;   // [Xb;Db] contiguous
    bf16_t* Db   = (bf16_t*)ws; ws += (size_t)N_D * D_IN * 2;
    bf16_t* Wxb  = (bf16_t*)ws; ws += (size_t)REP * D_IN * 2;
    bf16_t* Wdb  = (bf16_t*)ws; ws += (size_t)REP * D_IN * 2;
    bf16_t* Xw   = (bf16_t*)ws; ws += (size_t)N_Q * REP * 2;    // [Xw;Dw] contiguous
    bf16_t* Dw   = (bf16_t*)ws; ws += (size_t)N_D * REP * 2;
    float*  wvec = (float*)ws;  ws += (size_t)N_D * 4;
    float*  part = (float*)ws;  ws += (size_t)(N_D / 256) * N_Q * 4;

    constexpr int PREP_N = (N_Q * D_IN + N_D * D_IN + 2 * REP * D_IN) / 4 + N_D;
    prep<<<(PREP_N + 255) / 256, 256, 0, stream>>>(
        X, D, Wx_w, Wd_w, Xb, Db, Wxb, Wdb, R, enc, pos, We_w, wvec);

    proj_pipe<<<dim3(REP / 128, (N_Q + N_D) / 256), 256, 0, stream>>>(
        Xb, Wxb, Wdb, Wx_b, Wd_b, Xw);

    sim_pipe8<<<dim3(N_D / 256, N_Q / 256), 512, 0, stream>>>(Xw, Dw, wvec, part);

    final_reduce<<<(N_Q + 255) / 256, 256, 0, stream>>>(part, We_b, out);
}

// Round 12
// 110.327 us; speedup vs baseline: 1.0459x; 1.0291x over previous
//
#include <hip/hip_runtime.h>
#include <hip/hip_bf16.h>

#define N_Q 4096
#define N_D 8192
#define D_IN 768
#define REP 768
#define NENC 129
#define RDIM 4

typedef __bf16 bf16_t;
typedef __bf16 bf16x4 __attribute__((ext_vector_type(4)));
typedef __bf16 bf16x8 __attribute__((ext_vector_type(8)));
typedef float f32x4 __attribute__((ext_vector_type(4)));

__device__ __forceinline__ void gload_lds16(const void* g, void* l) {
    __builtin_amdgcn_global_load_lds(
        (const __attribute__((address_space(1))) void*)g,
        (__attribute__((address_space(3))) void*)l,
        16, 0, 0);
}

__device__ __forceinline__ unsigned ldsAddr(const void* p) {
    return (unsigned)(unsigned long long)(const __attribute__((address_space(3))) char*)p;
}

template <int OFF>
__device__ __forceinline__ bf16x8 ds_read_b128_off(unsigned addr) {
    bf16x8 r;
    asm volatile("ds_read_b128 %0, %1 offset:%2" : "=v"(r) : "v"(addr), "i"(OFF));
    return r;
}

#define BAR() asm volatile("s_barrier" ::: "memory")
#define LGKM0() do { asm volatile("s_waitcnt lgkmcnt(0)" ::: "memory"); \
                     __builtin_amdgcn_sched_barrier(0); } while (0)
#define VM(n) asm volatile("s_waitcnt vmcnt(" #n ")" ::: "memory")
#define SB0() __builtin_amdgcn_sched_barrier(0)

// ---------------- prep: all f32->bf16 casts + per-doc weight, ONE launch ----------------
__device__ __forceinline__ void cast4(const float* __restrict__ s, bf16_t* __restrict__ d, int i) {
    const float4 v = reinterpret_cast<const float4*>(s)[i];
    bf16x4 o;
    o[0] = (bf16_t)v.x; o[1] = (bf16_t)v.y; o[2] = (bf16_t)v.z; o[3] = (bf16_t)v.w;
    reinterpret_cast<bf16x4*>(d)[i] = o;
}

__global__ void prep(const float* __restrict__ X, const float* __restrict__ D,
                     const float* __restrict__ Wx, const float* __restrict__ Wd,
                     bf16_t* __restrict__ Xb, bf16_t* __restrict__ Db,
                     bf16_t* __restrict__ Wxb, bf16_t* __restrict__ Wdb,
                     const float* __restrict__ R, const float* __restrict__ enc,
                     const float* __restrict__ pos, const float* __restrict__ We_w,
                     float* __restrict__ wout) {
    constexpr int C_X  = N_Q * D_IN / 4;
    constexpr int C_D  = C_X + N_D * D_IN / 4;
    constexpr int C_WX = C_D + REP * D_IN / 4;
    constexpr int C_WD = C_WX + REP * D_IN / 4;
    const int i = blockIdx.x * blockDim.x + threadIdx.x;
    if (i < C_X)       cast4(X,  Xb,  i);
    else if (i < C_D)  cast4(D,  Db,  i - C_X);
    else if (i < C_WX) cast4(Wx, Wxb, i - C_D);
    else if (i < C_WD) cast4(Wd, Wdb, i - C_WX);
    else {
        const int j = i - C_WD;
        if (j < N_D) {
            const float r = R[j];
            int best = 0;
            float bd = fabsf(r - enc[0]);
            for (int e = 1; e < NENC; ++e) {
                const float d = fabsf(r - enc[e]);
                if (d < bd) { bd = d; best = e; }   // strict <, matches jnp.argmin
            }
            float s = 0.f;
            for (int d = 0; d < RDIM; ++d) s += pos[best * RDIM + d] * We_w[d];
            wout[j] = s;
        }
    }
}

// ================= proj: R8/R9's PROVEN 4-wave 256x128 ring-3 core (unchanged) =================
__device__ __forceinline__ void gemm_core4(const bf16_t* __restrict__ gAj0,
                                           const bf16_t* __restrict__ gAj1,
                                           const bf16_t* __restrict__ gAj2,
                                           const bf16_t* __restrict__ gAj3,
                                           const bf16_t* __restrict__ gBj0,
                                           const bf16_t* __restrict__ gBj1,
                                           bf16_t (*As)[8192], bf16_t (*Bs)[4096],
                                           int dOff, unsigned baseA, unsigned baseB,
                                           f32x4 (&acc)[8][4]) {
#define STAGE_A(kt) do { const int _k = (kt); const int _b = _k % 3; \
        char* _d = (char*)(As[_b]) + dOff; \
        gload_lds16(gAj0 + _k * 32, _d); \
        gload_lds16(gAj1 + _k * 32, _d + 4096); \
        gload_lds16(gAj2 + _k * 32, _d + 8192); \
        gload_lds16(gAj3 + _k * 32, _d + 12288); } while (0)
#define STAGE_B(kt) do { const int _k = (kt); const int _b = _k % 3; \
        char* _d = (char*)(Bs[_b]) + dOff; \
        gload_lds16(gBj0 + _k * 32, _d); \
        gload_lds16(gBj1 + _k * 32, _d + 4096); } while (0)

    STAGE_A(0); STAGE_B(0);
    STAGE_A(1); STAGE_B(1);
    VM(6);
    BAR();

#pragma unroll 3
    for (int k = 0; k < 24; ++k) {
        const int pre = (k + 2 < 24) ? k + 2 : 23;
        const unsigned aA = baseA + (unsigned)((k % 3) * 16384);
        const unsigned aB = baseB + (unsigned)((k % 3) * 8192);

        bf16x8 a[4], b[4];
        a[0] = ds_read_b128_off<0>(aA);
        a[1] = ds_read_b128_off<1024>(aA);
        a[2] = ds_read_b128_off<2048>(aA);
        a[3] = ds_read_b128_off<3072>(aA);
        b[0] = ds_read_b128_off<0>(aB);
        b[1] = ds_read_b128_off<1024>(aB);
        b[2] = ds_read_b128_off<2048>(aB);
        b[3] = ds_read_b128_off<3072>(aB);
        STAGE_A(pre);
        LGKM0();
        __builtin_amdgcn_s_setprio(1);
#pragma unroll
        for (int mi = 0; mi < 4; ++mi)
#pragma unroll
            for (int ni = 0; ni < 4; ++ni)
                acc[mi][ni] = __builtin_amdgcn_mfma_f32_16x16x32_bf16(a[mi], b[ni], acc[mi][ni], 0, 0, 0);
        __builtin_amdgcn_s_setprio(0);

        bf16x8 c[4];
        c[0] = ds_read_b128_off<4096>(aA);
        c[1] = ds_read_b128_off<5120>(aA);
        c[2] = ds_read_b128_off<6144>(aA);
        c[3] = ds_read_b128_off<7168>(aA);
        STAGE_B(pre);
        LGKM0();
        __builtin_amdgcn_s_setprio(1);
#pragma unroll
        for (int mi = 0; mi < 4; ++mi)
#pragma unroll
            for (int ni = 0; ni < 4; ++ni)
                acc[mi + 4][ni] = __builtin_amdgcn_mfma_f32_16x16x32_bf16(c[mi], b[ni], acc[mi + 4][ni], 0, 0, 0);
        __builtin_amdgcn_s_setprio(0);

        VM(6);
        BAR();
    }
#undef STAGE_A
#undef STAGE_B
}

__global__ __launch_bounds__(256, 2)
void proj_pipe(const bf16_t* __restrict__ Ain, const bf16_t* __restrict__ Wxb,
               const bf16_t* __restrict__ Wdb, const float* __restrict__ bx,
               const float* __restrict__ bd, bf16_t* __restrict__ Cout) {
    __shared__ bf16_t As[3][8192];
    __shared__ bf16_t Bs[3][4096];

    const bool isX = blockIdx.y < (N_Q / 256);
    const bf16_t* Bw = isX ? Wxb : Wdb;
    const float* bias = isX ? bx : bd;
    const long mBase = (long)blockIdx.y * 256;
    const long nBase = (long)blockIdx.x * 128;

    const int t = threadIdx.x;
    const int lane = t & 63;
    const int wid = t >> 6;
    const int lr = lane & 15;
    const int lq = lane >> 4;
    const int wr = wid >> 1;
    const int wc = wid & 1;
    const int dOff = wid * 1024;
    const bf16_t* gAj[4]; const bf16_t* gBj[2];
#pragma unroll
    for (int j = 0; j < 4; ++j) {
        const int pj = t * 16 + j * 4096;
        const int qj = pj ^ (((pj >> 7) & 7) << 4);
        gAj[j] = Ain + (mBase + (qj >> 6)) * (long)REP + ((qj & 63) >> 1);
    }
#pragma unroll
    for (int j = 0; j < 2; ++j) {
        const int pj = t * 16 + j * 4096;
        const int qj = pj ^ (((pj >> 7) & 7) << 4);
        gBj[j] = Bw + (nBase + (qj >> 6)) * (long)REP + ((qj & 63) >> 1);
    }
    const int rA = wr * 128 + lr;
    const unsigned apA = (unsigned)((rA * 64 + lq * 16) ^ (((rA >> 1) & 7) << 4));
    const int rB = wc * 64 + lr;
    const unsigned apB = (unsigned)((rB * 64 + lq * 16) ^ (((rB >> 1) & 7) << 4));
    const unsigned baseA = ldsAddr(&As[0][0]) + apA;
    const unsigned baseB = ldsAddr(&Bs[0][0]) + apB;

    f32x4 acc[8][4] = {};
    gemm_core4(gAj[0], gAj[1], gAj[2], gAj[3], gBj[0], gBj[1],
               As, Bs, dOff, baseA, baseB, acc);

#pragma unroll
    for (int ni = 0; ni < 4; ++ni) {
        const int col = (int)nBase + wc * 64 + ni * 16 + lr;
        const float bv = bias[col];
#pragma unroll
        for (int mi = 0; mi < 8; ++mi)
#pragma unroll
            for (int j = 0; j < 4; ++j) {
                const long row = mBase + wr * 128 + mi * 16 + lq * 4 + j;
                Cout[row * (long)REP + col] = (bf16_t)(acc[mi][ni][j] + bv);
            }
    }
}

// ================= sim: 256x256, 8 waves, BK=64, 8-phase — KT BUG FIXED =================
// K = 768, BK = 64 -> EXACTLY 12 K-tiles (R10/R11 looped 24 = K doubled = OOB reads = NaN).
// LDS: AsL/BsL[2 dbuf][2 half][128x64 bf16] (16KB half-tiles) + red + dump = 148KB.
// Swizzle: p = q ^ (((q>>8)&7)<<4); key = row bits 1-3 (frag offsets multiples of 16 rows
//   -> key invariant); ks slice = ^64 (XOR-safe below key bits).
// Per phase: {reads || 1 half-tile stage + SB0} -> BAR -> lgkm0 -> prio1 16 MFMA prio0 -> BAR.
// vmcnt(2) at P4 & P8 only (FIFO-drains exactly the next tile's 8 loads).
// Tail (kt=10): stages for kt>=12 go to dump (source clamped in-bounds, data discarded,
//   counts unchanged).
__global__ __launch_bounds__(512, 2)
void sim_8ph(const bf16_t* __restrict__ A, const bf16_t* __restrict__ B,
             const float* __restrict__ wcol, float* __restrict__ partial) {
    __shared__ bf16_t AsL[2][2][8192];   // [buf][half][128 rows x 64 K] = 16KB half-tiles
    __shared__ bf16_t BsL[2][2][8192];
    __shared__ float red[4][256];
    __shared__ char dump[16384];         // tail-stage sink

    const int t = threadIdx.x;
    const int lane = t & 63;
    const int wid = t >> 6;
    const int lr = lane & 15;
    const int lq = lane >> 4;
    const int wr = wid >> 2;   // 0..1 m-half (=A half)
    const int wc = wid & 3;    // 0..3 n-strip; B half = wc>>1
    const long mBase = (long)blockIdx.y * 256;
    const long nBase = (long)blockIdx.x * 256;

    // stage sources (inverse-swizzled): physical p = t*16 + s*8192; q = p ^ (((p>>8)&7)<<4)
    const char* gAsrc[2]; const char* gBsrc[2];
#pragma unroll
    for (int s = 0; s < 2; ++s) {
        const int p = t * 16 + s * 8192;
        const int q = p ^ (((p >> 8) & 7) << 4);
        const int row = q >> 7;      // 0..127 within half
        const int cb  = q & 127;     // byte within 128B (K=64) chunk of the row
        gAsrc[s] = (const char*)A + ((long)(mBase + row)) * (REP * 2) + cb;
        gBsrc[s] = (const char*)B + ((long)(nBase + row)) * (REP * 2) + cb;
    }
    const int dW = wid * 1024;   // wave-uniform dest base (HW adds lane*16)

    // loop-invariant read addresses
    const unsigned swzL = (unsigned)((lr * 128 + lq * 16) ^ (((lr >> 1) & 7) << 4));
    const unsigned aA00 = ldsAddr(&AsL[0][wr][0]) + swzL;          // buf0, ks0
    const unsigned aA01 = aA00 ^ 64;                               // buf0, ks1
    const unsigned aA10 = aA00 + 32768;                            // buf1
    const unsigned aA11 = aA10 ^ 64;
    const unsigned bB00 = ldsAddr(&BsL[0][wc >> 1][0]) + (unsigned)((wc & 1) * 8192) + swzL;
    const unsigned bB01 = bB00 ^ 64;
    const unsigned bB10 = bB00 + 32768;
    const unsigned bB11 = bB10 ^ 64;

#define STG_A(HALF, KT_) do { const int _k0 = (KT_); const bool _ok = (_k0 < 12); \
        const int _kt = _ok ? _k0 : 11; \
        char* _d = _ok ? ((char*)(&AsL[_kt & 1][(HALF)][0]) + dW) : (dump + dW); \
        gload_lds16(gAsrc[0] + (HALF) * 196608 + _kt * 128, _d); \
        gload_lds16(gAsrc[1] + (HALF) * 196608 + _kt * 128, _d + 8192); \
        SB0(); } while (0)
#define STG_B(HALF, KT_) do { const int _k0 = (KT_); const bool _ok = (_k0 < 12); \
        const int _kt = _ok ? _k0 : 11; \
        char* _d = _ok ? ((char*)(&BsL[_kt & 1][(HALF)][0]) + dW) : (dump + dW); \
        gload_lds16(gBsrc[0] + (HALF) * 196608 + _kt * 128, _d); \
        gload_lds16(gBsrc[1] + (HALF) * 196608 + _kt * 128, _d + 8192); \
        SB0(); } while (0)

#define READ_A(MI, A0, A1) do { \
        aR[0][0] = ds_read_b128_off<(MI)*8192 + 0>(A0); \
        aR[1][0] = ds_read_b128_off<(MI)*8192 + 2048>(A0); \
        aR[2][0] = ds_read_b128_off<(MI)*8192 + 4096>(A0); \
        aR[3][0] = ds_read_b128_off<(MI)*8192 + 6144>(A0); \
        aR[0][1] = ds_read_b128_off<(MI)*8192 + 0>(A1); \
        aR[1][1] = ds_read_b128_off<(MI)*8192 + 2048>(A1); \
        aR[2][1] = ds_read_b128_off<(MI)*8192 + 4096>(A1); \
        aR[3][1] = ds_read_b128_off<(MI)*8192 + 6144>(A1); } while (0)
#define READ_B(NI, B0, B1) do { \
        bR[0][0] = ds_read_b128_off<(NI)*4096 + 0>(B0); \
        bR[1][0] = ds_read_b128_off<(NI)*4096 + 2048>(B0); \
        bR[0][1] = ds_read_b128_off<(NI)*4096 + 0>(B1); \
        bR[1][1] = ds_read_b128_off<(NI)*4096 + 2048>(B1); } while (0)
#define MFMA16(MI, NI) do { \
        __builtin_amdgcn_s_setprio(1); \
        _Pragma("unroll") for (int f = 0; f < 4; ++f) \
        _Pragma("unroll") for (int g = 0; g < 2; ++g) { \
            acc[(MI)*4+f][(NI)*2+g] = __builtin_amdgcn_mfma_f32_16x16x32_bf16(aR[f][0], bR[g][0], acc[(MI)*4+f][(NI)*2+g], 0, 0, 0); \
            acc[(MI)*4+f][(NI)*2+g] = __builtin_amdgcn_mfma_f32_16x16x32_bf16(aR[f][1], bR[g][1], acc[(MI)*4+f][(NI)*2+g], 0, 0, 0); } \
        __builtin_amdgcn_s_setprio(0); } while (0)

    bf16x8 aR[4][2], bR[2][2];
    f32x4 acc[8][4] = {};

    // prologue: kt0 all 4 halves + Ah0(kt1) = 10 loads; VM(2) drains kt0's 8.
    STG_A(0, 0); STG_A(1, 0); STG_B(0, 0); STG_B(1, 0); STG_A(0, 1);
    VM(2);
    BAR();

#pragma unroll 1
    for (int kt = 0; kt < 12; kt += 2) {
        // P1: Q(m0,n0) of kt (buf0)
        READ_A(0, aA00, aA01); READ_B(0, bB00, bB01); STG_A(1, kt + 1);
        BAR(); LGKM0(); MFMA16(0, 0); BAR();
        // P2: Q(m0,n1)
        READ_B(1, bB00, bB01); STG_B(0, kt + 1);
        BAR(); LGKM0(); MFMA16(0, 1); BAR();
        // P3: Q(m1,n1)
        READ_A(1, aA00, aA01); STG_B(1, kt + 1);
        BAR(); LGKM0(); MFMA16(1, 1); BAR();
        // P4: Q(m1,n0)  [VM(2): kt+1's 8 loads retired, Ah0(kt+2) stays in flight]
        READ_B(0, bB00, bB01); STG_A(0, kt + 2);
        VM(2); BAR(); LGKM0(); MFMA16(1, 0); BAR();
        // P5: Q(m0,n0) of kt+1 (buf1)
        READ_A(0, aA10, aA11); READ_B(0, bB10, bB11); STG_A(1, kt + 2);
        BAR(); LGKM0(); MFMA16(0, 0); BAR();
        // P6: Q(m0,n1)
        READ_B(1, bB10, bB11); STG_B(0, kt + 2);
        BAR(); LGKM0(); MFMA16(0, 1); BAR();
        // P7: Q(m1,n1)
        READ_A(1, aA10, aA11); STG_B(1, kt + 2);
        BAR(); LGKM0(); MFMA16(1, 1); BAR();
        // P8: Q(m1,n0)  [VM(2): kt+2's 8 loads retired, Ah0(kt+3) stays in flight]
        READ_B(0, bB10, bB11); STG_A(0, kt + 3);
        VM(2); BAR(); LGKM0(); MFMA16(1, 0); BAR();
    }
    asm volatile("s_waitcnt vmcnt(0) lgkmcnt(0)" ::: "memory");

#undef STG_A
#undef STG_B
#undef READ_A
#undef READ_B
#undef MFMA16

    // epilogue: f(a)*w, reduce over n cols. D layout: row=(l>>4)*4+j, col=l&15 per 16x16
    float wreg[4];
#pragma unroll
    for (int ni = 0; ni < 4; ++ni) wreg[ni] = wcol[nBase + wc * 64 + ni * 16 + lr];

#pragma unroll
    for (int mi = 0; mi < 8; ++mi)
#pragma unroll
        for (int j = 0; j < 4; ++j) {
            float s = 0.f;
#pragma unroll
            for (int ni = 0; ni < 4; ++ni) {
                const float av = acc[mi][ni][j];
                s += av * fabsf(av) * wreg[ni];
            }
            s += __shfl_xor(s, 1);
            s += __shfl_xor(s, 2);
            s += __shfl_xor(s, 4);
            s += __shfl_xor(s, 8);
            if (lr == 0) red[wc][wr * 128 + mi * 16 + lq * 4 + j] = s;
        }
    __syncthreads();
    if (t < 256)
        partial[(long)blockIdx.x * N_Q + mBase + t]
            = red[0][t] + red[1][t] + red[2][t] + red[3][t];
}

// ---------------- final: out[i] = sum_nb partial[nb][i] + We_b ----------------
__global__ void final_reduce(const float* __restrict__ partial, const float* __restrict__ We_b,
                             float* __restrict__ out) {
    int i = blockIdx.x * blockDim.x + threadIdx.x;
    if (i < N_Q) {
        float s = 0.f;
        for (int nb = 0; nb < N_D / 256; ++nb) s += partial[(long)nb * N_Q + i];
        out[i] = s + We_b[0];
    }
}

extern "C" void kernel_launch(void* const* d_in, const int* in_sizes, int n_in,
                              void* d_out, int out_size, void* d_ws, size_t ws_size,
                              hipStream_t stream) {
    const float* X    = (const float*)d_in[0];
    const float* D    = (const float*)d_in[1];
    const float* R    = (const float*)d_in[2];
    const float* Wx_w = (const float*)d_in[3];
    const float* Wx_b = (const float*)d_in[4];
    const float* Wd_w = (const float*)d_in[5];
    const float* Wd_b = (const float*)d_in[6];
    const float* We_w = (const float*)d_in[7];
    const float* We_b = (const float*)d_in[8];
    const float* enc  = (const float*)d_in[9];
    const float* pos  = (const float*)d_in[10];
    float* out = (float*)d_out;

    char* ws = (char*)d_ws;
    bf16_t* Xb   = (bf16_t*)ws; ws += (size_t)N_Q * D_IN * 2;   // [Xb;Db] contiguous
    bf16_t* Db   = (bf16_t*)ws; ws += (size_t)N_D * D_IN * 2;
    bf16_t* Wxb  = (bf16_t*)ws; ws += (size_t)REP * D_IN * 2;
    bf16_t* Wdb  = (bf16_t*)ws; ws += (size_t)REP * D_IN * 2;
    bf16_t* Xw   = (bf16_t*)ws; ws += (size_t)N_Q * REP * 2;    // [Xw;Dw] contiguous
    bf16_t* Dw   = (bf16_t*)ws; ws += (size_t)N_D * REP * 2;
    float*  wvec = (float*)ws;  ws += (size_t)N_D * 4;
    float*  part = (float*)ws;  ws += (size_t)(N_D / 256) * N_Q * 4;

    constexpr int PREP_N = (N_Q * D_IN + N_D * D_IN + 2 * REP * D_IN) / 4 + N_D;
    prep<<<(PREP_N + 255) / 256, 256, 0, stream>>>(
        X, D, Wx_w, Wd_w, Xb, Db, Wxb, Wdb, R, enc, pos, We_w, wvec);

    proj_pipe<<<dim3(REP / 128, (N_Q + N_D) / 256), 256, 0, stream>>>(
        Xb, Wxb, Wdb, Wx_b, Wd_b, Xw);

    sim_8ph<<<dim3(N_D / 256, N_Q / 256), 512, 0, stream>>>(Xw, Dw, wvec, part);

    final_reduce<<<(N_Q + 255) / 256, 256, 0, stream>>>(part, We_b, out);
}

// Round 13
// 109.602 us; speedup vs baseline: 1.0528x; 1.0066x over previous
//
#include <hip/hip_runtime.h>
#include <hip/hip_bf16.h>

#define N_Q 4096
#define N_D 8192
#define D_IN 768
#define REP 768
#define NENC 129
#define RDIM 4

typedef __bf16 bf16_t;
typedef __bf16 bf16x4 __attribute__((ext_vector_type(4)));
typedef __bf16 bf16x8 __attribute__((ext_vector_type(8)));
typedef float f32x4 __attribute__((ext_vector_type(4)));

__device__ __forceinline__ void gload_lds16(const void* g, void* l) {
    __builtin_amdgcn_global_load_lds(
        (const __attribute__((address_space(1))) void*)g,
        (__attribute__((address_space(3))) void*)l,
        16, 0, 0);
}

__device__ __forceinline__ unsigned ldsAddr(const void* p) {
    return (unsigned)(unsigned long long)(const __attribute__((address_space(3))) char*)p;
}

template <int OFF>
__device__ __forceinline__ bf16x8 ds_read_b128_off(unsigned addr) {
    bf16x8 r;
    asm volatile("ds_read_b128 %0, %1 offset:%2" : "=v"(r) : "v"(addr), "i"(OFF));
    return r;
}

#define BAR() asm volatile("s_barrier" ::: "memory")
#define LGKM0() do { asm volatile("s_waitcnt lgkmcnt(0)" ::: "memory"); \
                     __builtin_amdgcn_sched_barrier(0); } while (0)
#define VM(n) asm volatile("s_waitcnt vmcnt(" #n ")" ::: "memory")
#define SB0() __builtin_amdgcn_sched_barrier(0)

// ---------------- prep: all f32->bf16 casts + per-doc weight, ONE launch ----------------
__device__ __forceinline__ void cast4(const float* __restrict__ s, bf16_t* __restrict__ d, int i) {
    const float4 v = reinterpret_cast<const float4*>(s)[i];
    bf16x4 o;
    o[0] = (bf16_t)v.x; o[1] = (bf16_t)v.y; o[2] = (bf16_t)v.z; o[3] = (bf16_t)v.w;
    reinterpret_cast<bf16x4*>(d)[i] = o;
}

__global__ void prep(const float* __restrict__ X, const float* __restrict__ D,
                     const float* __restrict__ Wx, const float* __restrict__ Wd,
                     bf16_t* __restrict__ Xb, bf16_t* __restrict__ Db,
                     bf16_t* __restrict__ Wxb, bf16_t* __restrict__ Wdb,
                     const float* __restrict__ R, const float* __restrict__ enc,
                     const float* __restrict__ pos, const float* __restrict__ We_w,
                     float* __restrict__ wout) {
    constexpr int C_X  = N_Q * D_IN / 4;
    constexpr int C_D  = C_X + N_D * D_IN / 4;
    constexpr int C_WX = C_D + REP * D_IN / 4;
    constexpr int C_WD = C_WX + REP * D_IN / 4;
    const int i = blockIdx.x * blockDim.x + threadIdx.x;
    if (i < C_X)       cast4(X,  Xb,  i);
    else if (i < C_D)  cast4(D,  Db,  i - C_X);
    else if (i < C_WX) cast4(Wx, Wxb, i - C_D);
    else if (i < C_WD) cast4(Wd, Wdb, i - C_WX);
    else {
        const int j = i - C_WD;
        if (j < N_D) {
            const float r = R[j];
            int best = 0;
            float bd = fabsf(r - enc[0]);
            for (int e = 1; e < NENC; ++e) {
                const float d = fabsf(r - enc[e]);
                if (d < bd) { bd = d; best = e; }   // strict <, matches jnp.argmin
            }
            float s = 0.f;
            for (int d = 0; d < RDIM; ++d) s += pos[best * RDIM + d] * We_w[d];
            wout[j] = s;
        }
    }
}

// ================= proj: R8/R9's PROVEN 4-wave 256x128 ring-3 core (unchanged) =================
__device__ __forceinline__ void gemm_core4(const bf16_t* __restrict__ gAj0,
                                           const bf16_t* __restrict__ gAj1,
                                           const bf16_t* __restrict__ gAj2,
                                           const bf16_t* __restrict__ gAj3,
                                           const bf16_t* __restrict__ gBj0,
                                           const bf16_t* __restrict__ gBj1,
                                           bf16_t (*As)[8192], bf16_t (*Bs)[4096],
                                           int dOff, unsigned baseA, unsigned baseB,
                                           f32x4 (&acc)[8][4]) {
#define STAGE_A(kt) do { const int _k = (kt); const int _b = _k % 3; \
        char* _d = (char*)(As[_b]) + dOff; \
        gload_lds16(gAj0 + _k * 32, _d); \
        gload_lds16(gAj1 + _k * 32, _d + 4096); \
        gload_lds16(gAj2 + _k * 32, _d + 8192); \
        gload_lds16(gAj3 + _k * 32, _d + 12288); } while (0)
#define STAGE_B(kt) do { const int _k = (kt); const int _b = _k % 3; \
        char* _d = (char*)(Bs[_b]) + dOff; \
        gload_lds16(gBj0 + _k * 32, _d); \
        gload_lds16(gBj1 + _k * 32, _d + 4096); } while (0)

    STAGE_A(0); STAGE_B(0);
    STAGE_A(1); STAGE_B(1);
    VM(6);
    BAR();

#pragma unroll 3
    for (int k = 0; k < 24; ++k) {
        const int pre = (k + 2 < 24) ? k + 2 : 23;
        const unsigned aA = baseA + (unsigned)((k % 3) * 16384);
        const unsigned aB = baseB + (unsigned)((k % 3) * 8192);

        bf16x8 a[4], b[4];
        a[0] = ds_read_b128_off<0>(aA);
        a[1] = ds_read_b128_off<1024>(aA);
        a[2] = ds_read_b128_off<2048>(aA);
        a[3] = ds_read_b128_off<3072>(aA);
        b[0] = ds_read_b128_off<0>(aB);
        b[1] = ds_read_b128_off<1024>(aB);
        b[2] = ds_read_b128_off<2048>(aB);
        b[3] = ds_read_b128_off<3072>(aB);
        STAGE_A(pre);
        LGKM0();
        __builtin_amdgcn_s_setprio(1);
#pragma unroll
        for (int mi = 0; mi < 4; ++mi)
#pragma unroll
            for (int ni = 0; ni < 4; ++ni)
                acc[mi][ni] = __builtin_amdgcn_mfma_f32_16x16x32_bf16(a[mi], b[ni], acc[mi][ni], 0, 0, 0);
        __builtin_amdgcn_s_setprio(0);

        bf16x8 c[4];
        c[0] = ds_read_b128_off<4096>(aA);
        c[1] = ds_read_b128_off<5120>(aA);
        c[2] = ds_read_b128_off<6144>(aA);
        c[3] = ds_read_b128_off<7168>(aA);
        STAGE_B(pre);
        LGKM0();
        __builtin_amdgcn_s_setprio(1);
#pragma unroll
        for (int mi = 0; mi < 4; ++mi)
#pragma unroll
            for (int ni = 0; ni < 4; ++ni)
                acc[mi + 4][ni] = __builtin_amdgcn_mfma_f32_16x16x32_bf16(c[mi], b[ni], acc[mi + 4][ni], 0, 0, 0);
        __builtin_amdgcn_s_setprio(0);

        VM(6);
        BAR();
    }
#undef STAGE_A
#undef STAGE_B
}

__global__ __launch_bounds__(256, 2)
void proj_pipe(const bf16_t* __restrict__ Ain, const bf16_t* __restrict__ Wxb,
               const bf16_t* __restrict__ Wdb, const float* __restrict__ bx,
               const float* __restrict__ bd, bf16_t* __restrict__ Cout) {
    __shared__ bf16_t As[3][8192];
    __shared__ bf16_t Bs[3][4096];

    const bool isX = blockIdx.y < (N_Q / 256);
    const bf16_t* Bw = isX ? Wxb : Wdb;
    const float* bias = isX ? bx : bd;
    const long mBase = (long)blockIdx.y * 256;
    const long nBase = (long)blockIdx.x * 128;

    const int t = threadIdx.x;
    const int lane = t & 63;
    const int wid = t >> 6;
    const int lr = lane & 15;
    const int lq = lane >> 4;
    const int wr = wid >> 1;
    const int wc = wid & 1;
    const int dOff = wid * 1024;
    const bf16_t* gAj[4]; const bf16_t* gBj[2];
#pragma unroll
    for (int j = 0; j < 4; ++j) {
        const int pj = t * 16 + j * 4096;
        const int qj = pj ^ (((pj >> 7) & 7) << 4);
        gAj[j] = Ain + (mBase + (qj >> 6)) * (long)REP + ((qj & 63) >> 1);
    }
#pragma unroll
    for (int j = 0; j < 2; ++j) {
        const int pj = t * 16 + j * 4096;
        const int qj = pj ^ (((pj >> 7) & 7) << 4);
        gBj[j] = Bw + (nBase + (qj >> 6)) * (long)REP + ((qj & 63) >> 1);
    }
    const int rA = wr * 128 + lr;
    const unsigned apA = (unsigned)((rA * 64 + lq * 16) ^ (((rA >> 1) & 7) << 4));
    const int rB = wc * 64 + lr;
    const unsigned apB = (unsigned)((rB * 64 + lq * 16) ^ (((rB >> 1) & 7) << 4));
    const unsigned baseA = ldsAddr(&As[0][0]) + apA;
    const unsigned baseB = ldsAddr(&Bs[0][0]) + apB;

    f32x4 acc[8][4] = {};
    gemm_core4(gAj[0], gAj[1], gAj[2], gAj[3], gBj[0], gBj[1],
               As, Bs, dOff, baseA, baseB, acc);

#pragma unroll
    for (int ni = 0; ni < 4; ++ni) {
        const int col = (int)nBase + wc * 64 + ni * 16 + lr;
        const float bv = bias[col];
#pragma unroll
        for (int mi = 0; mi < 8; ++mi)
#pragma unroll
            for (int j = 0; j < 4; ++j) {
                const long row = mBase + wr * 128 + mi * 16 + lq * 4 + j;
                Cout[row * (long)REP + col] = (bf16_t)(acc[mi][ni][j] + bv);
            }
    }
}

// ================= sim: 256x256, 8 waves, BK=64, 8-phase v2 =================
// v2 over R12: (1) TWO persistent B register sets (bR0 = n0-1 @P1, bR1 = n2-3 @P2;
//   P3 uses bR1, P4 uses bR0) -> P4/P8 B re-reads eliminated (28->24 ds_read/K-tile/wave);
// (2) stages reordered for slack: P1:{Ah1,Bh1}(kt+1), P2:{Bh0}(kt+1), P4:{Ah0}(kt+2)
//   -> binding half-tile now has 2-3 phases before its VM(2) drain (was 1).
// FIFO invariant (audited): carry into each half-iteration = 2 loads (next tile's Ah0);
//   VM(2) at P4/P8 retires exactly the next tile's remaining 8 loads. Overwrite windows:
//   every stage >=1 barrier after its region's readers' lgkm0 retirement. Tail: kt>=12
//   stages -> dump (counts uniform, sources clamped in-bounds).
__global__ __launch_bounds__(512, 2)
void sim_8ph(const bf16_t* __restrict__ A, const bf16_t* __restrict__ B,
             const float* __restrict__ wcol, float* __restrict__ partial) {
    __shared__ bf16_t AsL[2][2][8192];   // [buf][half][128 rows x 64 K] = 16KB half-tiles
    __shared__ bf16_t BsL[2][2][8192];
    __shared__ float red[4][256];
    __shared__ char dump[16384];         // tail-stage sink

    const int t = threadIdx.x;
    const int lane = t & 63;
    const int wid = t >> 6;
    const int lr = lane & 15;
    const int lq = lane >> 4;
    const int wr = wid >> 2;   // 0..1 m-half (=A half)
    const int wc = wid & 3;    // 0..3 n-strip; B half = wc>>1
    const long mBase = (long)blockIdx.y * 256;
    const long nBase = (long)blockIdx.x * 256;

    // stage sources (inverse-swizzled): physical p = t*16 + s*8192; q = p ^ (((p>>8)&7)<<4)
    const char* gAsrc[2]; const char* gBsrc[2];
#pragma unroll
    for (int s = 0; s < 2; ++s) {
        const int p = t * 16 + s * 8192;
        const int q = p ^ (((p >> 8) & 7) << 4);
        const int row = q >> 7;      // 0..127 within half
        const int cb  = q & 127;     // byte within 128B (K=64) chunk of the row
        gAsrc[s] = (const char*)A + ((long)(mBase + row)) * (REP * 2) + cb;
        gBsrc[s] = (const char*)B + ((long)(nBase + row)) * (REP * 2) + cb;
    }
    const int dW = wid * 1024;   // wave-uniform dest base (HW adds lane*16)

    // loop-invariant read addresses
    const unsigned swzL = (unsigned)((lr * 128 + lq * 16) ^ (((lr >> 1) & 7) << 4));
    const unsigned aA00 = ldsAddr(&AsL[0][wr][0]) + swzL;          // buf0
    const unsigned aA01 = aA00 ^ 64;
    const unsigned aA10 = aA00 + 32768;                            // buf1
    const unsigned aA11 = aA10 ^ 64;
    const unsigned bB00 = ldsAddr(&BsL[0][wc >> 1][0]) + (unsigned)((wc & 1) * 8192) + swzL;
    const unsigned bB01 = bB00 ^ 64;
    const unsigned bB10 = bB00 + 32768;
    const unsigned bB11 = bB10 ^ 64;

#define STG_A(HALF, KT_) do { const int _k0 = (KT_); const bool _ok = (_k0 < 12); \
        const int _kt = _ok ? _k0 : 11; \
        char* _d = _ok ? ((char*)(&AsL[_kt & 1][(HALF)][0]) + dW) : (dump + dW); \
        gload_lds16(gAsrc[0] + (HALF) * 196608 + _kt * 128, _d); \
        gload_lds16(gAsrc[1] + (HALF) * 196608 + _kt * 128, _d + 8192); \
        SB0(); } while (0)
#define STG_B(HALF, KT_) do { const int _k0 = (KT_); const bool _ok = (_k0 < 12); \
        const int _kt = _ok ? _k0 : 11; \
        char* _d = _ok ? ((char*)(&BsL[_kt & 1][(HALF)][0]) + dW) : (dump + dW); \
        gload_lds16(gBsrc[0] + (HALF) * 196608 + _kt * 128, _d); \
        gload_lds16(gBsrc[1] + (HALF) * 196608 + _kt * 128, _d + 8192); \
        SB0(); } while (0)

#define READ_A(MI, A0, A1) do { \
        aR[0][0] = ds_read_b128_off<(MI)*8192 + 0>(A0); \
        aR[1][0] = ds_read_b128_off<(MI)*8192 + 2048>(A0); \
        aR[2][0] = ds_read_b128_off<(MI)*8192 + 4096>(A0); \
        aR[3][0] = ds_read_b128_off<(MI)*8192 + 6144>(A0); \
        aR[0][1] = ds_read_b128_off<(MI)*8192 + 0>(A1); \
        aR[1][1] = ds_read_b128_off<(MI)*8192 + 2048>(A1); \
        aR[2][1] = ds_read_b128_off<(MI)*8192 + 4096>(A1); \
        aR[3][1] = ds_read_b128_off<(MI)*8192 + 6144>(A1); } while (0)
#define READ_B0(B0, B1) do { \
        bR0[0][0] = ds_read_b128_off<0>(B0); \
        bR0[1][0] = ds_read_b128_off<2048>(B0); \
        bR0[0][1] = ds_read_b128_off<0>(B1); \
        bR0[1][1] = ds_read_b128_off<2048>(B1); } while (0)
#define READ_B1(B0, B1) do { \
        bR1[0][0] = ds_read_b128_off<4096>(B0); \
        bR1[1][0] = ds_read_b128_off<6144>(B0); \
        bR1[0][1] = ds_read_b128_off<4096>(B1); \
        bR1[1][1] = ds_read_b128_off<6144>(B1); } while (0)
#define MFMA16(MI, NP, BB) do { \
        __builtin_amdgcn_s_setprio(1); \
        _Pragma("unroll") for (int f = 0; f < 4; ++f) \
        _Pragma("unroll") for (int g = 0; g < 2; ++g) { \
            acc[(MI)*4+f][(NP)*2+g] = __builtin_amdgcn_mfma_f32_16x16x32_bf16(aR[f][0], BB[g][0], acc[(MI)*4+f][(NP)*2+g], 0, 0, 0); \
            acc[(MI)*4+f][(NP)*2+g] = __builtin_amdgcn_mfma_f32_16x16x32_bf16(aR[f][1], BB[g][1], acc[(MI)*4+f][(NP)*2+g], 0, 0, 0); } \
        __builtin_amdgcn_s_setprio(0); } while (0)

    bf16x8 aR[4][2], bR0[2][2], bR1[2][2];
    f32x4 acc[8][4] = {};

    // prologue: kt0 all 4 halves + Ah0(kt1) = 10 loads; VM(2) retires kt0's 8; carry = 2.
    STG_A(0, 0); STG_A(1, 0); STG_B(0, 0); STG_B(1, 0); STG_A(0, 1);
    VM(2);
    BAR();

#pragma unroll 1
    for (int kt = 0; kt < 12; kt += 2) {
        // ---- P1: reads A-h(kt) m0-3 + B n0-1 -> bR0; stage Ah1,Bh1(kt+1) ----
        READ_A(0, aA00, aA01); READ_B0(bB00, bB01);
        STG_A(1, kt + 1); STG_B(1, kt + 1);
        BAR(); LGKM0(); MFMA16(0, 0, bR0); BAR();
        // ---- P2: reads B n2-3 -> bR1; stage Bh0(kt+1) ----
        READ_B1(bB00, bB01);
        STG_B(0, kt + 1);
        BAR(); LGKM0(); MFMA16(0, 1, bR1); BAR();
        // ---- P3: reads A m4-7; no stage ----
        READ_A(1, aA00, aA01);
        BAR(); LGKM0(); MFMA16(1, 1, bR1); BAR();
        // ---- P4: no reads; stage Ah0(kt+2); VM(2) -> tile kt+1 resident ----
        STG_A(0, kt + 2);
        VM(2); BAR(); MFMA16(1, 0, bR0); BAR();
        // ---- P5: tile kt+1 (buf1) ----
        READ_A(0, aA10, aA11); READ_B0(bB10, bB11);
        STG_A(1, kt + 2); STG_B(1, kt + 2);
        BAR(); LGKM0(); MFMA16(0, 0, bR0); BAR();
        // ---- P6 ----
        READ_B1(bB10, bB11);
        STG_B(0, kt + 2);
        BAR(); LGKM0(); MFMA16(0, 1, bR1); BAR();
        // ---- P7 ----
        READ_A(1, aA10, aA11);
        BAR(); LGKM0(); MFMA16(1, 1, bR1); BAR();
        // ---- P8: VM(2) -> tile kt+2 resident ----
        STG_A(0, kt + 3);
        VM(2); BAR(); MFMA16(1, 0, bR0); BAR();
    }
    asm volatile("s_waitcnt vmcnt(0) lgkmcnt(0)" ::: "memory");

#undef STG_A
#undef STG_B
#undef READ_A
#undef READ_B0
#undef READ_B1
#undef MFMA16

    // epilogue: f(a)*w, reduce over n cols. D layout: row=(l>>4)*4+j, col=l&15 per 16x16
    float wreg[4];
#pragma unroll
    for (int ni = 0; ni < 4; ++ni) wreg[ni] = wcol[nBase + wc * 64 + ni * 16 + lr];

#pragma unroll
    for (int mi = 0; mi < 8; ++mi)
#pragma unroll
        for (int j = 0; j < 4; ++j) {
            float s = 0.f;
#pragma unroll
            for (int ni = 0; ni < 4; ++ni) {
                const float av = acc[mi][ni][j];
                s += av * fabsf(av) * wreg[ni];
            }
            s += __shfl_xor(s, 1);
            s += __shfl_xor(s, 2);
            s += __shfl_xor(s, 4);
            s += __shfl_xor(s, 8);
            if (lr == 0) red[wc][wr * 128 + mi * 16 + lq * 4 + j] = s;
        }
    __syncthreads();
    if (t < 256)
        partial[(long)blockIdx.x * N_Q + mBase + t]
            = red[0][t] + red[1][t] + red[2][t] + red[3][t];
}

// ---------------- final: out[i] = sum_nb partial[nb][i] + We_b ----------------
__global__ void final_reduce(const float* __restrict__ partial, const float* __restrict__ We_b,
                             float* __restrict__ out) {
    int i = blockIdx.x * blockDim.x + threadIdx.x;
    if (i < N_Q) {
        float s = 0.f;
        for (int nb = 0; nb < N_D / 256; ++nb) s += partial[(long)nb * N_Q + i];
        out[i] = s + We_b[0];
    }
}

extern "C" void kernel_launch(void* const* d_in, const int* in_sizes, int n_in,
                              void* d_out, int out_size, void* d_ws, size_t ws_size,
                              hipStream_t stream) {
    const float* X    = (const float*)d_in[0];
    const float* D    = (const float*)d_in[1];
    const float* R    = (const float*)d_in[2];
    const float* Wx_w = (const float*)d_in[3];
    const float* Wx_b = (const float*)d_in[4];
    const float* Wd_w = (const float*)d_in[5];
    const float* Wd_b = (const float*)d_in[6];
    const float* We_w = (const float*)d_in[7];
    const float* We_b = (const float*)d_in[8];
    const float* enc  = (const float*)d_in[9];
    const float* pos  = (const float*)d_in[10];
    float* out = (float*)d_out;

    char* ws = (char*)d_ws;
    bf16_t* Xb   = (bf16_t*)ws; ws += (size_t)N_Q * D_IN * 2;   // [Xb;Db] contiguous
    bf16_t* Db   = (bf16_t*)ws; ws += (size_t)N_D * D_IN * 2;
    bf16_t* Wxb  = (bf16_t*)ws; ws += (size_t)REP * D_IN * 2;
    bf16_t* Wdb  = (bf16_t*)ws; ws += (size_t)REP * D_IN * 2;
    bf16_t* Xw   = (bf16_t*)ws; ws += (size_t)N_Q * REP * 2;    // [Xw;Dw] contiguous
    bf16_t* Dw   = (bf16_t*)ws; ws += (size_t)N_D * REP * 2;
    float*  wvec = (float*)ws;  ws += (size_t)N_D * 4;
    float*  part = (float*)ws;  ws += (size_t)(N_D / 256) * N_Q * 4;

    constexpr int PREP_N = (N_Q * D_IN + N_D * D_IN + 2 * REP * D_IN) / 4 + N_D;
    prep<<<(PREP_N + 255) / 256, 256, 0, stream>>>(
        X, D, Wx_w, Wd_w, Xb, Db, Wxb, Wdb, R, enc, pos, We_w, wvec);

    proj_pipe<<<dim3(REP / 128, (N_Q + N_D) / 256), 256, 0, stream>>>(
        Xb, Wxb, Wdb, Wx_b, Wd_b, Xw);

    sim_8ph<<<dim3(N_D / 256, N_Q / 256), 512, 0, stream>>>(Xw, Dw, wvec, part);

    final_reduce<<<(N_Q + 255) / 256, 256, 0, stream>>>(part, We_b, out);
}